// Round 1
// baseline (124.467 us; speedup 1.0000x reference)
//
#include <hip/hip_runtime.h>
#include <cfloat>

// Emu3 VQ-VAE vector quantizer argmin (exact-rounding match to numpy ref):
//   x [9216,4] f32 (channels-last gather from [1,4,4,48,48])
//   e [32768,4] f32
//   out[n] = argmin_k fl( fl(x2+e2) - 2*fl(dot) ), first-min tie semantics.
//
// Round 6:
//  - BLOCK 256 -> 512 (same grid=768, same ROWS=12): occupancy was GRID-
//    limited at 3 waves/SIMD (768 blk x 4 waves / 1024 SIMDs); VALUBusy 68%
//    was vmcnt-stall, not issue-bound. 512-thread blocks give 3 blk/CU x
//    8 waves = 24 waves/CU = 6 waves/SIMD with zero extra VALU work and
//    zero extra L2 traffic (per-thread entries halve, per-block sweep same).
//  - waves_per_eu(6,8): keep allocator at <=~80 VGPR so all 6 waves/SIMD
//    are resident (live set ~62 -> allocates 64, no spill).
//  - (Round 5 carried) x-components block-uniform -> readfirstlane to SGPR;
//    packed fp32 v_pk_fma_f32 over row pairs; ping-pong K loop; arithmetic
//    kept bitwise identical to the reference rounding (absmax must stay 0).

typedef float v2f __attribute__((ext_vector_type(2)));

#define ROWS  12
#define RP    (ROWS / 2)
#define BLOCK 512
#define WAVES (BLOCK / 64)
#define NK    32768
#define EPT   2
#define CHUNK (BLOCK * EPT)   // 1024

__device__ __forceinline__ float rlf(float v) {
    return __builtin_bit_cast(float,
        __builtin_amdgcn_readfirstlane(__builtin_bit_cast(int, v)));
}

__global__ __launch_bounds__(BLOCK)
__attribute__((amdgpu_waves_per_eu(6, 8)))
void vq_argmin_kernel(const float* __restrict__ hs,
                      const float4* __restrict__ cb,
                      int* __restrict__ out)
{
    __shared__ float sRD[WAVES * ROWS];
    __shared__ int   sRI[WAVES * ROWS];

    const int tid = threadIdx.x;
    const int rowbase = blockIdx.x * ROWS;

    v2f xp0[RP], xp1[RP], xp2[RP], xp3[RP], x2p[RP];  // uniform -> SGPR pairs
    float best[ROWS];
    int   bidx[ROWS];   // stores chunk index m; k = m*BLOCK + tid

    #pragma unroll
    for (int p = 0; p < RP; ++p) {
        float c0[2], c1[2], c2[2], c3[2], q[2];
        #pragma unroll
        for (int h = 0; h < 2; ++h) {
            int n = rowbase + 2 * p + h;
            int t = n / 2304;                 // 2304 = 48*48
            int rem = n - t * 2304;
            const float* ptr = hs + t * 9216 + rem;   // + c*2304 per channel
            float a0 = ptr[0], a1 = ptr[2304], a2 = ptr[4608], a3 = ptr[6912];
            c0[h] = a0; c1[h] = a1; c2[h] = a2; c3[h] = a3;
            q[h] = __fadd_rn(__fadd_rn(__fadd_rn(__fmul_rn(a0, a0),
                                                 __fmul_rn(a1, a1)),
                                       __fmul_rn(a2, a2)),
                             __fmul_rn(a3, a3));
        }
        xp0[p] = (v2f){rlf(c0[0]), rlf(c0[1])};
        xp1[p] = (v2f){rlf(c1[0]), rlf(c1[1])};
        xp2[p] = (v2f){rlf(c2[0]), rlf(c2[1])};
        xp3[p] = (v2f){rlf(c3[0]), rlf(c3[1])};
        x2p[p] = (v2f){rlf(q[0]),  rlf(q[1])};
    }
    #pragma unroll
    for (int r = 0; r < ROWS; ++r) { best[r] = FLT_MAX; bidx[r] = 0; }

    float4 bufA[EPT], bufB[EPT];

    auto load_chunk = [&](float4* buf, int tb) {
        #pragma unroll
        for (int j = 0; j < EPT; ++j) buf[j] = cb[tb + tid + j * BLOCK];
    };
    auto compute_chunk = [&](const float4* buf, int tb) {
        #pragma unroll
        for (int j = 0; j < EPT; ++j) {
            float4 e = buf[j];
            float e2 = __fadd_rn(__fadd_rn(__fadd_rn(__fmul_rn(e.x, e.x),
                                                     __fmul_rn(e.y, e.y)),
                                           __fmul_rn(e.z, e.z)),
                                 __fmul_rn(e.w, e.w));
            v2f ex = {e.x, e.x}, ey = {e.y, e.y};
            v2f ez = {e.z, e.z}, ew = {e.w, e.w};
            v2f e2s = {e2, e2};
            int m = tb / BLOCK + j;           // uniform chunk index
            #pragma unroll
            for (int p = 0; p < RP; ++p) {
                v2f dot = xp0[p] * ex;
                dot = __builtin_elementwise_fma(xp1[p], ey, dot);
                dot = __builtin_elementwise_fma(xp2[p], ez, dot);
                dot = __builtin_elementwise_fma(xp3[p], ew, dot);
                v2f t1 = x2p[p] + e2s;
                v2f d  = __builtin_elementwise_fma(dot, (v2f){-2.f, -2.f}, t1);
                if (d.x < best[2 * p])     { best[2 * p] = d.x;     bidx[2 * p] = m; }
                if (d.y < best[2 * p + 1]) { best[2 * p + 1] = d.y; bidx[2 * p + 1] = m; }
            }
        }
    };

    // ---- ping-pong K loop: load one buffer while computing the other
    load_chunk(bufA, 0);
    for (int tb = 0; tb < NK; tb += 2 * CHUNK) {
        load_chunk(bufB, tb + CHUNK);
        compute_chunk(bufA, tb);
        int nb = tb + 2 * CHUNK < NK ? tb + 2 * CHUNK : 0;  // last: dummy reload
        load_chunk(bufA, nb);
        compute_chunk(bufB, tb + CHUNK);
    }

    // ---- expand chunk index -> full codebook index, then reduce
    int kk[ROWS];
    #pragma unroll
    for (int r = 0; r < ROWS; ++r) kk[r] = bidx[r] * BLOCK + tid;

    // wave-level lexicographic (dist, idx) butterfly reduction
    #pragma unroll
    for (int r = 0; r < ROWS; ++r) {
        float d = best[r]; int i = kk[r];
        #pragma unroll
        for (int off = 32; off >= 1; off >>= 1) {
            float d2 = __shfl_xor(d, off, 64);
            int   i2 = __shfl_xor(i, off, 64);
            if (d2 < d || (d2 == d && i2 < i)) { d = d2; i = i2; }
        }
        best[r] = d; kk[r] = i;
    }

    int wave = tid >> 6;
    if ((tid & 63) == 0) {
        #pragma unroll
        for (int r = 0; r < ROWS; ++r) {
            sRD[wave * ROWS + r] = best[r];
            sRI[wave * ROWS + r] = kk[r];
        }
    }
    __syncthreads();

    if (tid < ROWS) {
        float d = sRD[tid]; int i = sRI[tid];
        #pragma unroll
        for (int w = 1; w < WAVES; ++w) {
            float d2 = sRD[w * ROWS + tid];
            int   i2 = sRI[w * ROWS + tid];
            if (d2 < d || (d2 == d && i2 < i)) { d = d2; i = i2; }
        }
        out[rowbase + tid] = i;
    }
}

extern "C" void kernel_launch(void* const* d_in, const int* in_sizes, int n_in,
                              void* d_out, int out_size, void* d_ws, size_t ws_size,
                              hipStream_t stream)
{
    const float*  hs = (const float*)d_in[0];    // [1,4,4,48,48]
    const float4* cb = (const float4*)d_in[1];   // [32768,4]
    int* out = (int*)d_out;                      // [9216] int32

    const int nrows = 9216;
    dim3 grid(nrows / ROWS), block(BLOCK);
    vq_argmin_kernel<<<grid, block, 0, stream>>>(hs, cb, out);
}

// Round 2
// 122.906 us; speedup vs baseline: 1.0127x; 1.0127x over previous
//
#include <hip/hip_runtime.h>
#include <cfloat>

// Emu3 VQ-VAE vector quantizer argmin (exact-rounding match to numpy ref):
//   x [9216,4] f32 (channels-last gather from [1,4,4,48,48])
//   e [32768,4] f32
//   out[n] = argmin_k fl( fl(x2+e2) - 2*fl(dot) ), first-min tie semantics.
//
// Round 7:
//  - Round 6 post-mortem: BLOCK 512 doubled occupancy (26->47%) but time was
//    flat at 82.5us because waves_per_eu(6,8) squeezed the allocator to 32
//    VGPRs (< the ~40-reg live set of ping-pong buffers + best/bidx) ->
//    scratch/serialization wiped out the occupancy win. VALUBusy 68->71 only.
//  - Fix: keep BLOCK=512 (grid gives 6 waves/SIMD at 3 blocks/CU), restore
//    the round-5-proven waves_per_eu(3,4) register budget so the double
//    buffer stays register-resident (expect VGPR ~64, no spill). The hint
//    does not cap HW occupancy; VGPR=64 allows 8 waves/SIMD, grid limits to 6.
//  - (Carried) x-components block-uniform -> readfirstlane to SGPR; packed
//    fp32 v_pk_fma_f32 over row pairs; ping-pong K loop; arithmetic kept
//    bitwise identical to reference rounding (indices exact, absmax 0).

typedef float v2f __attribute__((ext_vector_type(2)));

#define ROWS  12
#define RP    (ROWS / 2)
#define BLOCK 512
#define WAVES (BLOCK / 64)
#define NK    32768
#define EPT   2
#define CHUNK (BLOCK * EPT)   // 1024

__device__ __forceinline__ float rlf(float v) {
    return __builtin_bit_cast(float,
        __builtin_amdgcn_readfirstlane(__builtin_bit_cast(int, v)));
}

__global__ __launch_bounds__(BLOCK)
__attribute__((amdgpu_waves_per_eu(3, 4)))
void vq_argmin_kernel(const float* __restrict__ hs,
                      const float4* __restrict__ cb,
                      int* __restrict__ out)
{
    __shared__ float sRD[WAVES * ROWS];
    __shared__ int   sRI[WAVES * ROWS];

    const int tid = threadIdx.x;
    const int rowbase = blockIdx.x * ROWS;

    v2f xp0[RP], xp1[RP], xp2[RP], xp3[RP], x2p[RP];  // uniform -> SGPR pairs
    float best[ROWS];
    int   bidx[ROWS];   // stores chunk index m; k = m*BLOCK + tid

    #pragma unroll
    for (int p = 0; p < RP; ++p) {
        float c0[2], c1[2], c2[2], c3[2], q[2];
        #pragma unroll
        for (int h = 0; h < 2; ++h) {
            int n = rowbase + 2 * p + h;
            int t = n / 2304;                 // 2304 = 48*48
            int rem = n - t * 2304;
            const float* ptr = hs + t * 9216 + rem;   // + c*2304 per channel
            float a0 = ptr[0], a1 = ptr[2304], a2 = ptr[4608], a3 = ptr[6912];
            c0[h] = a0; c1[h] = a1; c2[h] = a2; c3[h] = a3;
            q[h] = __fadd_rn(__fadd_rn(__fadd_rn(__fmul_rn(a0, a0),
                                                 __fmul_rn(a1, a1)),
                                       __fmul_rn(a2, a2)),
                             __fmul_rn(a3, a3));
        }
        xp0[p] = (v2f){rlf(c0[0]), rlf(c0[1])};
        xp1[p] = (v2f){rlf(c1[0]), rlf(c1[1])};
        xp2[p] = (v2f){rlf(c2[0]), rlf(c2[1])};
        xp3[p] = (v2f){rlf(c3[0]), rlf(c3[1])};
        x2p[p] = (v2f){rlf(q[0]),  rlf(q[1])};
    }
    #pragma unroll
    for (int r = 0; r < ROWS; ++r) { best[r] = FLT_MAX; bidx[r] = 0; }

    float4 bufA[EPT], bufB[EPT];

    auto load_chunk = [&](float4* buf, int tb) {
        #pragma unroll
        for (int j = 0; j < EPT; ++j) buf[j] = cb[tb + tid + j * BLOCK];
    };
    auto compute_chunk = [&](const float4* buf, int tb) {
        #pragma unroll
        for (int j = 0; j < EPT; ++j) {
            float4 e = buf[j];
            float e2 = __fadd_rn(__fadd_rn(__fadd_rn(__fmul_rn(e.x, e.x),
                                                     __fmul_rn(e.y, e.y)),
                                           __fmul_rn(e.z, e.z)),
                                 __fmul_rn(e.w, e.w));
            v2f ex = {e.x, e.x}, ey = {e.y, e.y};
            v2f ez = {e.z, e.z}, ew = {e.w, e.w};
            v2f e2s = {e2, e2};
            int m = tb / BLOCK + j;           // uniform chunk index
            #pragma unroll
            for (int p = 0; p < RP; ++p) {
                v2f dot = xp0[p] * ex;
                dot = __builtin_elementwise_fma(xp1[p], ey, dot);
                dot = __builtin_elementwise_fma(xp2[p], ez, dot);
                dot = __builtin_elementwise_fma(xp3[p], ew, dot);
                v2f t1 = x2p[p] + e2s;
                v2f d  = __builtin_elementwise_fma(dot, (v2f){-2.f, -2.f}, t1);
                if (d.x < best[2 * p])     { best[2 * p] = d.x;     bidx[2 * p] = m; }
                if (d.y < best[2 * p + 1]) { best[2 * p + 1] = d.y; bidx[2 * p + 1] = m; }
            }
        }
    };

    // ---- ping-pong K loop: load one buffer while computing the other
    load_chunk(bufA, 0);
    for (int tb = 0; tb < NK; tb += 2 * CHUNK) {
        load_chunk(bufB, tb + CHUNK);
        compute_chunk(bufA, tb);
        int nb = tb + 2 * CHUNK < NK ? tb + 2 * CHUNK : 0;  // last: dummy reload
        load_chunk(bufA, nb);
        compute_chunk(bufB, tb + CHUNK);
    }

    // ---- expand chunk index -> full codebook index, then reduce
    int kk[ROWS];
    #pragma unroll
    for (int r = 0; r < ROWS; ++r) kk[r] = bidx[r] * BLOCK + tid;

    // wave-level lexicographic (dist, idx) butterfly reduction
    #pragma unroll
    for (int r = 0; r < ROWS; ++r) {
        float d = best[r]; int i = kk[r];
        #pragma unroll
        for (int off = 32; off >= 1; off >>= 1) {
            float d2 = __shfl_xor(d, off, 64);
            int   i2 = __shfl_xor(i, off, 64);
            if (d2 < d || (d2 == d && i2 < i)) { d = d2; i = i2; }
        }
        best[r] = d; kk[r] = i;
    }

    int wave = tid >> 6;
    if ((tid & 63) == 0) {
        #pragma unroll
        for (int r = 0; r < ROWS; ++r) {
            sRD[wave * ROWS + r] = best[r];
            sRI[wave * ROWS + r] = kk[r];
        }
    }
    __syncthreads();

    if (tid < ROWS) {
        float d = sRD[tid]; int i = sRI[tid];
        #pragma unroll
        for (int w = 1; w < WAVES; ++w) {
            float d2 = sRD[w * ROWS + tid];
            int   i2 = sRI[w * ROWS + tid];
            if (d2 < d || (d2 == d && i2 < i)) { d = d2; i = i2; }
        }
        out[rowbase + tid] = i;
    }
}

extern "C" void kernel_launch(void* const* d_in, const int* in_sizes, int n_in,
                              void* d_out, int out_size, void* d_ws, size_t ws_size,
                              hipStream_t stream)
{
    const float*  hs = (const float*)d_in[0];    // [1,4,4,48,48]
    const float4* cb = (const float4*)d_in[1];   // [32768,4]
    int* out = (int*)d_out;                      // [9216] int32

    const int nrows = 9216;
    dim3 grid(nrows / ROWS), block(BLOCK);
    vq_argmin_kernel<<<grid, block, 0, stream>>>(hs, cb, out);
}

// Round 3
// 121.794 us; speedup vs baseline: 1.0219x; 1.0091x over previous
//
#include <hip/hip_runtime.h>
#include <cfloat>

// Emu3 VQ-VAE vector quantizer argmin (exact-rounding match to numpy ref):
//   x [9216,4] f32 (channels-last gather from [1,4,4,48,48])
//   e [32768,4] f32
//   out[n] = argmin_k fl( fl(x2+e2) - 2*fl(dot) ), first-min tie semantics.
//
// Round 8:
//  - Rounds 5/6/7 all land at 82-84us with occupancy 26/47/35% and VGPR
//    64/32/64: time is INVARIANT to occupancy and regalloc -> per-SIMD
//    instruction-stream bound, not latency-bound. VALUBusy pinned ~69%.
//  - Static floor: 9 instr (18 cyc) per (row,entry) -> ~35us ideal; measured
//    VALU-occupied time ~57us -> emitted stream has ~1.6x fat.
//  - Suspect: v2f packed path. v_pk_fma_f32 is half-rate on this chip (fp32
//    peak 157.3TF == scalar full rate), so packing gains ZERO ALU cycles but
//    forces broadcast register-pair materialization ({e.x,e.x} movs) and
//    risks scalarization double-issue. -> Rewrite inner loop in pure scalar
//    fp32: bitwise-identical rounding (pk fma == 2x scalar fma), no movs,
//    every op reads its uniform x operand straight from SGPR.
//  - Everything else held fixed (BLOCK=512, ROWS=12, grid=768=3 blk/CU,
//    ping-pong K loop, waves_per_eu(3,4)) -> near-single-variable codegen
//    experiment.

#define ROWS  12
#define BLOCK 512
#define WAVES (BLOCK / 64)
#define NK    32768
#define EPT   2
#define CHUNK (BLOCK * EPT)   // 1024

__device__ __forceinline__ float rlf(float v) {
    return __builtin_bit_cast(float,
        __builtin_amdgcn_readfirstlane(__builtin_bit_cast(int, v)));
}

__global__ __launch_bounds__(BLOCK)
__attribute__((amdgpu_waves_per_eu(3, 4)))
void vq_argmin_kernel(const float* __restrict__ hs,
                      const float4* __restrict__ cb,
                      int* __restrict__ out)
{
    __shared__ float sRD[WAVES * ROWS];
    __shared__ int   sRI[WAVES * ROWS];

    const int tid = threadIdx.x;
    const int rowbase = blockIdx.x * ROWS;

    // Block-uniform x components -> readfirstlane into SGPRs.
    float sx0[ROWS], sx1[ROWS], sx2[ROWS], sx3[ROWS], sq[ROWS];
    float best[ROWS];
    int   bidx[ROWS];   // stores chunk index m; k = m*BLOCK + tid

    #pragma unroll
    for (int r = 0; r < ROWS; ++r) {
        int n = rowbase + r;
        int t = n / 2304;                 // 2304 = 48*48
        int rem = n - t * 2304;
        const float* ptr = hs + t * 9216 + rem;   // + c*2304 per channel
        float a0 = ptr[0], a1 = ptr[2304], a2 = ptr[4608], a3 = ptr[6912];
        float q = __fadd_rn(__fadd_rn(__fadd_rn(__fmul_rn(a0, a0),
                                                __fmul_rn(a1, a1)),
                                      __fmul_rn(a2, a2)),
                            __fmul_rn(a3, a3));
        sx0[r] = rlf(a0); sx1[r] = rlf(a1);
        sx2[r] = rlf(a2); sx3[r] = rlf(a3);
        sq[r]  = rlf(q);
        best[r] = FLT_MAX; bidx[r] = 0;
    }

    float4 bufA[EPT], bufB[EPT];

    auto load_chunk = [&](float4* buf, int tb) {
        #pragma unroll
        for (int j = 0; j < EPT; ++j) buf[j] = cb[tb + tid + j * BLOCK];
    };
    auto compute_chunk = [&](const float4* buf, int tb) {
        #pragma unroll
        for (int j = 0; j < EPT; ++j) {
            float4 e = buf[j];
            float e2 = __fadd_rn(__fadd_rn(__fadd_rn(__fmul_rn(e.x, e.x),
                                                     __fmul_rn(e.y, e.y)),
                                           __fmul_rn(e.z, e.z)),
                                 __fmul_rn(e.w, e.w));
            int m = tb / BLOCK + j;           // uniform chunk index
            #pragma unroll
            for (int r = 0; r < ROWS; ++r) {
                float dot = __fmul_rn(sx0[r], e.x);
                dot = __fmaf_rn(sx1[r], e.y, dot);
                dot = __fmaf_rn(sx2[r], e.z, dot);
                dot = __fmaf_rn(sx3[r], e.w, dot);
                float t1 = __fadd_rn(sq[r], e2);
                float d  = __fmaf_rn(dot, -2.0f, t1);
                if (d < best[r]) { best[r] = d; bidx[r] = m; }
            }
        }
    };

    // ---- ping-pong K loop: load one buffer while computing the other
    load_chunk(bufA, 0);
    for (int tb = 0; tb < NK; tb += 2 * CHUNK) {
        load_chunk(bufB, tb + CHUNK);
        compute_chunk(bufA, tb);
        int nb = tb + 2 * CHUNK < NK ? tb + 2 * CHUNK : 0;  // last: dummy reload
        load_chunk(bufA, nb);
        compute_chunk(bufB, tb + CHUNK);
    }

    // ---- expand chunk index -> full codebook index, then reduce
    int kk[ROWS];
    #pragma unroll
    for (int r = 0; r < ROWS; ++r) kk[r] = bidx[r] * BLOCK + tid;

    // wave-level lexicographic (dist, idx) butterfly reduction
    #pragma unroll
    for (int r = 0; r < ROWS; ++r) {
        float d = best[r]; int i = kk[r];
        #pragma unroll
        for (int off = 32; off >= 1; off >>= 1) {
            float d2 = __shfl_xor(d, off, 64);
            int   i2 = __shfl_xor(i, off, 64);
            if (d2 < d || (d2 == d && i2 < i)) { d = d2; i = i2; }
        }
        best[r] = d; kk[r] = i;
    }

    int wave = tid >> 6;
    if ((tid & 63) == 0) {
        #pragma unroll
        for (int r = 0; r < ROWS; ++r) {
            sRD[wave * ROWS + r] = best[r];
            sRI[wave * ROWS + r] = kk[r];
        }
    }
    __syncthreads();

    if (tid < ROWS) {
        float d = sRD[tid]; int i = sRI[tid];
        #pragma unroll
        for (int w = 1; w < WAVES; ++w) {
            float d2 = sRD[w * ROWS + tid];
            int   i2 = sRI[w * ROWS + tid];
            if (d2 < d || (d2 == d && i2 < i)) { d = d2; i = i2; }
        }
        out[rowbase + tid] = i;
    }
}

extern "C" void kernel_launch(void* const* d_in, const int* in_sizes, int n_in,
                              void* d_out, int out_size, void* d_ws, size_t ws_size,
                              hipStream_t stream)
{
    const float*  hs = (const float*)d_in[0];    // [1,4,4,48,48]
    const float4* cb = (const float4*)d_in[1];   // [32768,4]
    int* out = (int*)d_out;                      // [9216] int32

    const int nrows = 9216;
    dim3 grid(nrows / ROWS), block(BLOCK);
    vq_argmin_kernel<<<grid, block, 0, stream>>>(hs, cb, out);
}